// Round 4
// baseline (194.381 us; speedup 1.0000x reference)
//
#include <hip/hip_runtime.h>
#include <hip/hip_bf16.h>
#include <math.h>

// Problem constants
#define Bb 4
#define Tt 1024
#define Cc 1024
#define Hh 16
#define Dd 64

typedef __attribute__((ext_vector_type(8))) _Float16 half8;
typedef __attribute__((ext_vector_type(4))) _Float16 half4;
typedef __attribute__((ext_vector_type(4))) float floatx4;

// Fragment-swizzled layout for an [R x 1024] f16 matrix:
//   addr(row,k) = (row>>4)*16384 + (k>>3)*128 + (row&15)*8 + (k&7)
// A wave's 16x16x32-MFMA operand fragment (rows 16-aligned, k 32-aligned) is
// base + lane*8 elems -> one coalesced global_load_dwordx4, and each fragment
// is 1024 B CONTIGUOUS -> global_load_lds stages it as a linear copy.

__device__ __forceinline__ void gload_lds16(const _Float16* g, const _Float16* l)
{
    __builtin_amdgcn_global_load_lds(
        (const __attribute__((address_space(1))) void*)g,
        (__attribute__((address_space(3))) void*)l, 16, 0, 0);
}

// ---------------------------------------------------------------------------
// prep_all: merged convert + weight-prep (one dispatch; round-11 verified).
// blocks [0,256):    x fp32 [4096][1024] -> xh f16 frag-swizzled
// blocks [256,1280): W[z][1024][1024] fp32 -> Wt[z] f16 transposed+swizzled
// ---------------------------------------------------------------------------
struct PrepP { const float* x; _Float16* xh; const float* W[4]; _Float16* out[4]; };

__global__ __launch_bounds__(256) void prep_all(PrepP p)
{
    if (blockIdx.x < 256) {
        const int m16 = blockIdx.x;
        const int r   = threadIdx.x & 15;
        const int kc0 = threadIdx.x >> 4;
        const float* src = p.x + (size_t)(m16 * 16 + r) * 1024;
        _Float16*   dst = p.xh + (size_t)m16 * 16384 + r * 8;
#pragma unroll
        for (int c8 = 0; c8 < 8; ++c8) {
            const int kc = kc0 + c8 * 16;
            float4 a = *(const float4*)(src + kc * 8);
            float4 b = *(const float4*)(src + kc * 8 + 4);
            half8 h;
            h[0] = (_Float16)a.x; h[1] = (_Float16)a.y; h[2] = (_Float16)a.z; h[3] = (_Float16)a.w;
            h[4] = (_Float16)b.x; h[5] = (_Float16)b.y; h[6] = (_Float16)b.z; h[7] = (_Float16)b.w;
            *(half8*)(dst + kc * 128) = h;
        }
        return;
    }
    const int bid2 = blockIdx.x - 256;
    const int z    = bid2 >> 8;
    const int rem  = bid2 & 255;
    const int n0   = (rem & 15) * 64;
    const int k0   = (rem >> 4) * 64;
    const float* __restrict__ W = p.W[z];
    _Float16* __restrict__ outp = p.out[z];
    __shared__ float tile[64][65];
    const int tr  = threadIdx.x >> 4;
    const int tc4 = (threadIdx.x & 15) * 4;

#pragma unroll
    for (int i = 0; i < 4; ++i) {
        const int kk = tr + i * 16;
        float4 v = *(const float4*)(W + (size_t)(k0 + kk) * 1024 + n0 + tc4);
        tile[kk][tc4 + 0] = v.x;
        tile[kk][tc4 + 1] = v.y;
        tile[kk][tc4 + 2] = v.z;
        tile[kk][tc4 + 3] = v.w;
    }
    __syncthreads();
#pragma unroll
    for (int i = 0; i < 4; ++i) {
        half4 h;
#pragma unroll
        for (int c = 0; c < 4; ++c) h[c] = (_Float16)tile[tc4 + c][tr + i * 16];
        _Float16* dst = outp + (size_t)((n0 >> 4) + i) * 16384
                        + ((k0 + tc4) >> 3) * 128 + tr * 8 + (tc4 & 7);
        *(half4*)dst = h;
    }
}

// ---------------------------------------------------------------------------
// gemm_qkv: ROUND-3 REWRITE — 2-phase double-buffered pipeline (T3 minimum
// recipe). BK=32, 2x16KB LDS buffers, ONE barrier per K-step, stage(t+1)
// issued BEFORE ds_read/MFMA(t) so the end-of-iter vmcnt drain is mostly
// satisfied. (Round-2 single-buffered 2-barrier version: 44.8 us, MfmaUtil
// 21% -- barrier drain serialized stage and compute.)
// Output epilogue/layouts unchanged from the verified round-10 version.
// ---------------------------------------------------------------------------
struct QkvP { const _Float16* Wt[3]; const float* bias[3];
              _Float16* qb; _Float16* kb; _Float16* vt; };

__global__ __launch_bounds__(256) void gemm_qkv(const _Float16* __restrict__ xh, QkvP p)
{
    const int z = blockIdx.z;
    const _Float16* __restrict__ Wt   = p.Wt[z];
    const float* __restrict__    bias = p.bias[z];

    const int tid  = threadIdx.x;
    const int lane = tid & 63;
    const int w    = tid >> 6;
    const int wr   = w >> 1, wc = w & 1;
    const int quad = lane >> 4;
    const int l15  = lane & 15;
    const int bm   = blockIdx.x * 128;
    const int bn   = blockIdx.y * 128;

    // double-buffered BK=32 tiles: 8 A-frags + 8 B-frags of 1 KB per buffer
    __shared__ __align__(16) _Float16 As[2][8][512];
    __shared__ __align__(16) _Float16 Bs[2][8][512];

    // wave w stages A-frags {2w, 2w+1} and B-frags {2w, 2w+1}
    const _Float16* ga[2];
    const _Float16* gb[2];
#pragma unroll
    for (int c = 0; c < 2; ++c) {
        ga[c] = xh + (size_t)((bm >> 4) + w * 2 + c) * 16384 + lane * 8;
        gb[c] = Wt + (size_t)((bn >> 4) + w * 2 + c) * 16384 + lane * 8;
    }

    floatx4 acc[4][4];
#pragma unroll
    for (int i = 0; i < 4; ++i)
#pragma unroll
        for (int j = 0; j < 4; ++j)
            acc[i][j] = (floatx4){0.f, 0.f, 0.f, 0.f};

    // prologue: stage K-step 0 into buffer 0
#pragma unroll
    for (int c = 0; c < 2; ++c) {
        gload_lds16(ga[c], &As[0][w * 2 + c][0]);
        gload_lds16(gb[c], &Bs[0][w * 2 + c][0]);
    }
    __syncthreads();

    for (int t = 0; t < 32; ++t) {
        const int cur = t & 1;
        // issue next-step stage FIRST (in flight across ds_read + MFMA)
        if (t < 31) {
            const size_t ko = (size_t)(t + 1) * 512;
#pragma unroll
            for (int c = 0; c < 2; ++c) {
                gload_lds16(ga[c] + ko, &As[cur ^ 1][w * 2 + c][0]);
                gload_lds16(gb[c] + ko, &Bs[cur ^ 1][w * 2 + c][0]);
            }
        }
        // compute current buffer
        half8 af[4], bf[4];
#pragma unroll
        for (int i = 0; i < 4; ++i)
            af[i] = *(const half8*)&As[cur][wr * 4 + i][lane * 8];
#pragma unroll
        for (int j = 0; j < 4; ++j)
            bf[j] = *(const half8*)&Bs[cur][wc * 4 + j][lane * 8];
#pragma unroll
        for (int i = 0; i < 4; ++i)
#pragma unroll
            for (int j = 0; j < 4; ++j)
                acc[i][j] = __builtin_amdgcn_mfma_f32_16x16x32_f16(
                    af[i], bf[j], acc[i][j], 0, 0, 0);
        __syncthreads();  // drains the (mostly-complete) prefetch + guards swap
    }

    if (z == 2) {
        // v -> per-bh (d,t) frag-swizzle; 4 consecutive t at fixed d = half4
#pragma unroll
        for (int j = 0; j < 4; ++j) {
            const int col = bn + wc * 64 + j * 16 + l15;
            const int h  = col >> 6;
            const float bj = bias[col];
#pragma unroll
            for (int i = 0; i < 4; ++i) {
                const int t0 = bm + wr * 64 + i * 16 + quad * 4;
                const int bh = (t0 >> 10) * 16 + h;
                const int tm = t0 & 1023;
                half4 pk;
#pragma unroll
                for (int r = 0; r < 4; ++r) pk[r] = (_Float16)(acc[i][j][r] + bj);
                *(half4*)(p.vt + (size_t)bh * 65536 + (size_t)j * 16384
                          + (tm >> 3) * 128 + l15 * 8 + (tm & 7)) = pk;
            }
        }
    } else {
        // q/k -> per-bh (t,d) frag-swizzle
        _Float16* outp = (z == 0) ? p.qb : p.kb;
#pragma unroll
        for (int j = 0; j < 4; ++j) {
            const int col = bn + wc * 64 + j * 16 + l15;
            const int h  = col >> 6;
            const int dd = col & 63;
            const float bj = bias[col];
            const int doff = (dd >> 3) * 128 + (dd & 7);
#pragma unroll
            for (int i = 0; i < 4; ++i) {
#pragma unroll
                for (int r = 0; r < 4; ++r) {
                    const int tg = bm + wr * 64 + i * 16 + quad * 4 + r;
                    const int bh = (tg >> 10) * 16 + h;
                    const int tm = tg & 1023;
                    outp[(size_t)bh * 65536 + (tm >> 4) * 1024 + doff + (tm & 15) * 8] =
                        (_Float16)(acc[i][j][r] + bj);
                }
            }
        }
    }
}

// ---------------------------------------------------------------------------
// attn_mfma (round-10 configuration — verified; round-11's 512-thread variant
// doubled K/V traffic and regressed). BARRIER-FREE: frag-direct Q/K/V loads,
// wave-private P in LDS, fixed-max softmax + ones-MFMA row sums.
// 4 waves x 32 q-rows, 128 q-rows/block; grid (64,8) x 256: x = bh.
// ---------------------------------------------------------------------------
__global__ __launch_bounds__(256) void attn_mfma(
    const _Float16* __restrict__ qb, const _Float16* __restrict__ kb,
    const _Float16* __restrict__ vt, const float* __restrict__ padj,
    _Float16* __restrict__ yh)
{
    __shared__ __align__(16) _Float16 Ps[4][2048];  // wave-private P

    const int tid  = threadIdx.x;
    const int lane = tid & 63;
    const int w    = tid >> 6;
    const int quad = lane >> 4;
    const int l15  = lane & 15;
    const int bh   = blockIdx.x;
    const int q0   = blockIdx.y * 128;
    const int b    = bh >> 4;
    const int h    = bh & 15;

    const _Float16* qf = qb + (size_t)bh * 65536;
    const _Float16* kf = kb + (size_t)bh * 65536;
    const _Float16* vf = vt + (size_t)bh * 65536;
    const float*    pk_row = padj + b * Tt;

    // Q frags: register-resident for entire K-loop (B-operand of S^T)
    half8 bq[2][2];
#pragma unroll
    for (int ks = 0; ks < 2; ++ks)
#pragma unroll
        for (int nq = 0; nq < 2; ++nq)
            bq[ks][nq] = *(const half8*)(qf + (size_t)((q0 >> 4) + w * 2 + nq) * 1024
                                         + ks * 512 + lane * 8);
    float kq[2];
#pragma unroll
    for (int nq = 0; nq < 2; ++nq)
        kq[nq] = 1.0f - pk_row[q0 + w * 32 + nq * 16 + l15];

    floatx4 O[2][4];
    floatx4 l_acc[2];
#pragma unroll
    for (int mi = 0; mi < 2; ++mi) {
#pragma unroll
        for (int dj = 0; dj < 4; ++dj) O[mi][dj] = (floatx4){0.f, 0.f, 0.f, 0.f};
        l_acc[mi] = (floatx4){0.f, 0.f, 0.f, 0.f};
    }
    half8 ones;
#pragma unroll
    for (int j = 0; j < 8; ++j) ones[j] = (_Float16)1.0f;

    constexpr float SC = 0.18033688011112042f;  // 0.125 * log2(e)

    for (int kt = 0; kt < Tt; kt += 64) {
        // direct frag loads: K (A-operand), V (B-operand)
        half8 ak[2][4], bv[2][4];
#pragma unroll
        for (int ks = 0; ks < 2; ++ks)
#pragma unroll
            for (int mk = 0; mk < 4; ++mk)
                ak[ks][mk] = *(const half8*)(kf + (size_t)((kt >> 4) + mk) * 1024
                                             + ks * 512 + lane * 8);
#pragma unroll
        for (int ks = 0; ks < 2; ++ks)
#pragma unroll
            for (int dj = 0; dj < 4; ++dj)
                bv[ks][dj] = *(const half8*)(vf + (size_t)dj * 16384 + (kt >> 3) * 128
                                             + ks * 512 + lane * 8);
        float4 kk4[4];
#pragma unroll
        for (int mk = 0; mk < 4; ++mk)
            kk4[mk] = *(const float4*)(pk_row + kt + mk * 16 + quad * 4);

        // S^T = K Q^T : C[m=key(quad*4+r)][n=qrow(l15)]
        floatx4 ST[4][2];
#pragma unroll
        for (int mk = 0; mk < 4; ++mk)
#pragma unroll
            for (int nq = 0; nq < 2; ++nq)
                ST[mk][nq] = (floatx4){0.f, 0.f, 0.f, 0.f};
#pragma unroll
        for (int ks = 0; ks < 2; ++ks)
#pragma unroll
            for (int mk = 0; mk < 4; ++mk)
#pragma unroll
                for (int nq = 0; nq < 2; ++nq)
                    ST[mk][nq] = __builtin_amdgcn_mfma_f32_16x16x32_f16(
                        ak[ks][mk], bq[ks][nq], ST[mk][nq], 0, 0, 0);

        // fixed-max softmax + wave-private P write (conflict-free b64)
#pragma unroll
        for (int mk = 0; mk < 4; ++mk) {
            const float kkr[4] = {1.0f - kk4[mk].x, 1.0f - kk4[mk].y,
                                  1.0f - kk4[mk].z, 1.0f - kk4[mk].w};
#pragma unroll
            for (int nq = 0; nq < 2; ++nq) {
                half4 pk;
#pragma unroll
                for (int r = 0; r < 4; ++r) {
                    const float e = __builtin_amdgcn_exp2f(ST[mk][nq][r] * SC);
                    const float pv = (kq[nq] == 0.0f) ? 1.0f : kkr[r] * e;
                    pk[r] = (_Float16)pv;
                }
                *(half4*)&Ps[w][((mk * 2 + (quad >> 1)) * 32 + nq * 16 + l15) * 8
                               + (quad & 1) * 4] = pk;
            }
        }
        // same-wave RAW on Ps -> compiler lgkmcnt; no barrier needed

        // O += P V ; l += P @ ones
#pragma unroll
        for (int ks = 0; ks < 2; ++ks) {
            half8 ap[2];
#pragma unroll
            for (int mi = 0; mi < 2; ++mi)
                ap[mi] = *(const half8*)&Ps[w][((ks * 4 + quad) * 32 + mi * 16 + l15) * 8];
#pragma unroll
            for (int mi = 0; mi < 2; ++mi) {
#pragma unroll
                for (int dj = 0; dj < 4; ++dj)
                    O[mi][dj] = __builtin_amdgcn_mfma_f32_16x16x32_f16(
                        ap[mi], bv[ks][dj], O[mi][dj], 0, 0, 0);
                l_acc[mi] = __builtin_amdgcn_mfma_f32_16x16x32_f16(
                    ap[mi], ones, l_acc[mi], 0, 0, 0);
            }
        }
    }

    // epilogue: normalize, write yh frag-swizzled (for LDS-free proj)
#pragma unroll
    for (int mi = 0; mi < 2; ++mi) {
#pragma unroll
        for (int r = 0; r < 4; ++r) {
            const int rowl  = w * 32 + mi * 16 + quad * 4 + r;
            const int token = b * Tt + q0 + rowl;
            const float inv = 1.0f / l_acc[mi][r];
            const size_t tb = (size_t)(token >> 4) * 16384 + (token & 15) * 8;
#pragma unroll
            for (int dj = 0; dj < 4; ++dj) {
                const int col = h * 64 + dj * 16 + l15;
                yh[tb + (col >> 3) * 128 + (col & 7)] = (_Float16)(O[mi][dj][r] * inv);
            }
        }
    }
}

// ---------------------------------------------------------------------------
// gemm_proj: LDS-free frag-direct (round 9/10, verified). 128x64 tiles,
// grid (32,16) = 512 blocks, x = m-tile.
// ---------------------------------------------------------------------------
__global__ __launch_bounds__(256) void gemm_proj(const _Float16* __restrict__ Ay,
                                                 const _Float16* __restrict__ Bt,
                                                 const float* __restrict__ bias,
                                                 float* __restrict__ out)
{
    const int tid  = threadIdx.x;
    const int lane = tid & 63;
    const int w    = tid >> 6;
    const int quad = lane >> 4;
    const int l15  = lane & 15;
    const int bm   = blockIdx.x * 128;
    const int bn   = blockIdx.y * 64;

    const _Float16* Ap[2];
    const _Float16* Bp[4];
#pragma unroll
    for (int i = 0; i < 2; ++i)
        Ap[i] = Ay + (size_t)((bm >> 4) + w * 2 + i) * 16384 + lane * 8;
#pragma unroll
    for (int j = 0; j < 4; ++j)
        Bp[j] = Bt + (size_t)((bn >> 4) + j) * 16384 + lane * 8;

    floatx4 acc[2][4];
#pragma unroll
    for (int i = 0; i < 2; ++i)
#pragma unroll
        for (int j = 0; j < 4; ++j)
            acc[i][j] = (floatx4){0.f, 0.f, 0.f, 0.f};

    half8 a0[2], b0[4];
#pragma unroll
    for (int i = 0; i < 2; ++i) a0[i] = *(const half8*)(Ap[i]);
#pragma unroll
    for (int j = 0; j < 4; ++j) b0[j] = *(const half8*)(Bp[j]);

    for (int kt = 0; kt < 1024; kt += 64) {
        half8 a1[2], b1[4];
        const size_t o1 = (size_t)(kt + 32) * 16;
#pragma unroll
        for (int i = 0; i < 2; ++i) a1[i] = *(const half8*)(Ap[i] + o1);
#pragma unroll
        for (int j = 0; j < 4; ++j) b1[j] = *(const half8*)(Bp[j] + o1);
#pragma unroll
        for (int i = 0; i < 2; ++i)
#pragma unroll
            for (int j = 0; j < 4; ++j)
                acc[i][j] = __builtin_amdgcn_mfma_f32_16x16x32_f16(a0[i], b0[j], acc[i][j], 0, 0, 0);

        const size_t o2 = (kt + 64 < 1024) ? (size_t)(kt + 64) * 16 : 0;
#pragma unroll
        for (int i = 0; i < 2; ++i) a0[i] = *(const half8*)(Ap[i] + o2);
#pragma unroll
        for (int j = 0; j < 4; ++j) b0[j] = *(const half8*)(Bp[j] + o2);
#pragma unroll
        for (int i = 0; i < 2; ++i)
#pragma unroll
            for (int j = 0; j < 4; ++j)
                acc[i][j] = __builtin_amdgcn_mfma_f32_16x16x32_f16(a1[i], b1[j], acc[i][j], 0, 0, 0);
    }

#pragma unroll
    for (int j = 0; j < 4; ++j) {
        const int col = bn + j * 16 + l15;
        const float bj = bias[col];
#pragma unroll
        for (int i = 0; i < 2; ++i) {
            const int row = bm + w * 32 + i * 16 + quad * 4;
            float* o = out + (size_t)row * 1024 + col;
#pragma unroll
            for (int r = 0; r < 4; ++r)
                o[(size_t)r * 1024] = acc[i][j][r] + bj;
        }
    }
}

// ---------------------------------------------------------------------------
extern "C" void kernel_launch(void* const* d_in, const int* in_sizes, int n_in,
                              void* d_out, int out_size, void* d_ws, size_t ws_size,
                              hipStream_t stream)
{
    const float* x    = (const float*)d_in[0];
    const float* padj = (const float*)d_in[1];
    const float* Wq   = (const float*)d_in[2];
    const float* bq   = (const float*)d_in[3];
    const float* Wk   = (const float*)d_in[4];
    const float* bk   = (const float*)d_in[5];
    const float* Wv   = (const float*)d_in[6];
    const float* bv   = (const float*)d_in[7];
    const float* Wp   = (const float*)d_in[8];
    const float* bp   = (const float*)d_in[9];
    float* out = (float*)d_out;

    const size_t MB = 1024 * 1024;
    char* ws = (char*)d_ws;
    _Float16* xh  = (_Float16*)(ws);            //  8 MB (frag-swizzled)
    _Float16* Wt0 = (_Float16*)(ws +  8 * MB);  //  2 MB
    _Float16* Wt1 = (_Float16*)(ws + 10 * MB);  //  2 MB
    _Float16* Wt2 = (_Float16*)(ws + 12 * MB);  //  2 MB
    _Float16* Wtp = (_Float16*)(ws + 14 * MB);  //  2 MB
    _Float16* qb  = (_Float16*)(ws + 16 * MB);  //  8 MB (per-bh frag)
    _Float16* kb  = (_Float16*)(ws + 24 * MB);  //  8 MB (per-bh frag)
    _Float16* vtb = (_Float16*)(ws + 32 * MB);  //  8 MB (per-bh frag)
    _Float16* yh  = (_Float16*)(ws + 40 * MB);  //  8 MB (frag-swizzled) -> 48 MB

    PrepP pp;
    pp.x = x; pp.xh = xh;
    pp.W[0] = Wq; pp.W[1] = Wk; pp.W[2] = Wv; pp.W[3] = Wp;
    pp.out[0] = Wt0; pp.out[1] = Wt1; pp.out[2] = Wt2; pp.out[3] = Wtp;
    prep_all<<<1280, 256, 0, stream>>>(pp);

    QkvP qp;
    qp.Wt[0] = Wt0; qp.Wt[1] = Wt1; qp.Wt[2] = Wt2;
    qp.bias[0] = bq; qp.bias[1] = bk; qp.bias[2] = bv;
    qp.qb = qb; qp.kb = kb; qp.vt = vtb;
    gemm_qkv<<<dim3(32, 8, 3), 256, 0, stream>>>(xh, qp);

    attn_mfma<<<dim3(64, 8), 256, 0, stream>>>(qb, kb, vtb, padj, yh);

    gemm_proj<<<dim3(32, 16), 256, 0, stream>>>(yh, Wtp, bp, out);
}

// Round 6
// 183.829 us; speedup vs baseline: 1.0574x; 1.0574x over previous
//
#include <hip/hip_runtime.h>
#include <hip/hip_bf16.h>
#include <math.h>

// Problem constants
#define Bb 4
#define Tt 1024
#define Cc 1024
#define Hh 16
#define Dd 64

typedef __attribute__((ext_vector_type(8))) _Float16 half8;
typedef __attribute__((ext_vector_type(4))) _Float16 half4;
typedef __attribute__((ext_vector_type(4))) float floatx4;

// Fragment-swizzled layout for an [R x 1024] f16 matrix:
//   addr(row,k) = (row>>4)*16384 + (k>>3)*128 + (row&15)*8 + (k&7)
// A wave's 16x16x32-MFMA operand fragment (rows 16-aligned, k 32-aligned) is
// base + lane*8 elems -> one coalesced global_load_dwordx4, and each fragment
// is 1024 B CONTIGUOUS -> global_load_lds stages it as a linear copy.

__device__ __forceinline__ void gload_lds16(const _Float16* g, const _Float16* l)
{
    __builtin_amdgcn_global_load_lds(
        (const __attribute__((address_space(1))) void*)g,
        (__attribute__((address_space(3))) void*)l, 16, 0, 0);
}

// ---------------------------------------------------------------------------
// prep_all: merged convert + weight-prep (one dispatch; round-11 verified).
// blocks [0,256):    x fp32 [4096][1024] -> xh f16 frag-swizzled
// blocks [256,1280): W[z][1024][1024] fp32 -> Wt[z] f16 transposed+swizzled
// ---------------------------------------------------------------------------
struct PrepP { const float* x; _Float16* xh; const float* W[4]; _Float16* out[4]; };

__global__ __launch_bounds__(256) void prep_all(PrepP p)
{
    if (blockIdx.x < 256) {
        const int m16 = blockIdx.x;
        const int r   = threadIdx.x & 15;
        const int kc0 = threadIdx.x >> 4;
        const float* src = p.x + (size_t)(m16 * 16 + r) * 1024;
        _Float16*   dst = p.xh + (size_t)m16 * 16384 + r * 8;
#pragma unroll
        for (int c8 = 0; c8 < 8; ++c8) {
            const int kc = kc0 + c8 * 16;
            float4 a = *(const float4*)(src + kc * 8);
            float4 b = *(const float4*)(src + kc * 8 + 4);
            half8 h;
            h[0] = (_Float16)a.x; h[1] = (_Float16)a.y; h[2] = (_Float16)a.z; h[3] = (_Float16)a.w;
            h[4] = (_Float16)b.x; h[5] = (_Float16)b.y; h[6] = (_Float16)b.z; h[7] = (_Float16)b.w;
            *(half8*)(dst + kc * 128) = h;
        }
        return;
    }
    const int bid2 = blockIdx.x - 256;
    const int z    = bid2 >> 8;
    const int rem  = bid2 & 255;
    const int n0   = (rem & 15) * 64;
    const int k0   = (rem >> 4) * 64;
    const float* __restrict__ W = p.W[z];
    _Float16* __restrict__ outp = p.out[z];
    __shared__ float tile[64][65];
    const int tr  = threadIdx.x >> 4;
    const int tc4 = (threadIdx.x & 15) * 4;

#pragma unroll
    for (int i = 0; i < 4; ++i) {
        const int kk = tr + i * 16;
        float4 v = *(const float4*)(W + (size_t)(k0 + kk) * 1024 + n0 + tc4);
        tile[kk][tc4 + 0] = v.x;
        tile[kk][tc4 + 1] = v.y;
        tile[kk][tc4 + 2] = v.z;
        tile[kk][tc4 + 3] = v.w;
    }
    __syncthreads();
#pragma unroll
    for (int i = 0; i < 4; ++i) {
        half4 h;
#pragma unroll
        for (int c = 0; c < 4; ++c) h[c] = (_Float16)tile[tc4 + c][tr + i * 16];
        _Float16* dst = outp + (size_t)((n0 >> 4) + i) * 16384
                        + ((k0 + tc4) >> 3) * 128 + tr * 8 + (tc4 & 7);
        *(half4*)dst = h;
    }
}

// ---------------------------------------------------------------------------
// gemm_qkv: ROUND-4 — T3+T4 counted-vmcnt pipeline. Round-3's dbuf with
// __syncthreads() regressed (57 us): HIP barriers ALWAYS drain vmcnt(0), so
// the prefetch was waited on cold every iter. This version uses raw
// s_barrier + asm s_waitcnt vmcnt(N), never 0 in the main loop.
//   3 buffers x 16 KB (BK=32), 48 KB LDS -> still 3 blocks/CU.
//   Ledger (per wave, 4 loads/tile): prologue stages t0,t1 -> vmcnt(4)
//   [t0 landed] -> barrier. Iter t: ds_read buf[t%3]; stage t+2 into
//   buf[(t+2)%3] (all waves done reading it at t-1, barrier-protected);
//   16 MFMA; vmcnt(4) [t+1 landed, t+2 in flight]; s_barrier.
//   Tail: t=30 waits vmcnt(0); t=31 computes clean.
// Output epilogue/layouts unchanged from the verified round-10 version.
// ---------------------------------------------------------------------------
struct QkvP { const _Float16* Wt[3]; const float* bias[3];
              _Float16* qb; _Float16* kb; _Float16* vt; };

#define QKV_STEP(CUR, SBUF, TS, DOSTAGE, TAILWAIT)                          \
    {                                                                       \
        half8 af[4], bf[4];                                                 \
        _Pragma("unroll")                                                   \
        for (int i = 0; i < 4; ++i)                                         \
            af[i] = *(const half8*)&As[CUR][wr * 4 + i][lane * 8];          \
        _Pragma("unroll")                                                   \
        for (int j = 0; j < 4; ++j)                                         \
            bf[j] = *(const half8*)&Bs[CUR][wc * 4 + j][lane * 8];          \
        if (DOSTAGE) {                                                      \
            const size_t ko = (size_t)(TS) * 512;                           \
            _Pragma("unroll")                                               \
            for (int c = 0; c < 2; ++c) {                                   \
                gload_lds16(ga[c] + ko, &As[SBUF][w * 2 + c][0]);           \
                gload_lds16(gb[c] + ko, &Bs[SBUF][w * 2 + c][0]);           \
            }                                                               \
        }                                                                   \
        _Pragma("unroll")                                                   \
        for (int i = 0; i < 4; ++i)                                         \
            _Pragma("unroll")                                               \
            for (int j = 0; j < 4; ++j)                                     \
                acc[i][j] = __builtin_amdgcn_mfma_f32_16x16x32_f16(         \
                    af[i], bf[j], acc[i][j], 0, 0, 0);                      \
        if ((TAILWAIT) == 4)                                                \
            asm volatile("s_waitcnt vmcnt(4)" ::: "memory");                \
        else if ((TAILWAIT) == 0)                                           \
            asm volatile("s_waitcnt vmcnt(0)" ::: "memory");                \
        if ((TAILWAIT) >= 0) __builtin_amdgcn_s_barrier();                  \
    }

__global__ __launch_bounds__(256) void gemm_qkv(const _Float16* __restrict__ xh, QkvP p)
{
    const int z = blockIdx.z;
    const _Float16* __restrict__ Wt   = p.Wt[z];
    const float* __restrict__    bias = p.bias[z];

    const int tid  = threadIdx.x;
    const int lane = tid & 63;
    const int w    = tid >> 6;
    const int wr   = w >> 1, wc = w & 1;
    const int quad = lane >> 4;
    const int l15  = lane & 15;
    const int bm   = blockIdx.x * 128;
    const int bn   = blockIdx.y * 128;

    // triple-buffered BK=32 tiles: 8 A-frags + 8 B-frags of 1 KB per buffer
    __shared__ __align__(16) _Float16 As[3][8][512];
    __shared__ __align__(16) _Float16 Bs[3][8][512];

    // wave w stages A-frags {2w, 2w+1} and B-frags {2w, 2w+1}: 4 loads/tile
    const _Float16* ga[2];
    const _Float16* gb[2];
#pragma unroll
    for (int c = 0; c < 2; ++c) {
        ga[c] = xh + (size_t)((bm >> 4) + w * 2 + c) * 16384 + lane * 8;
        gb[c] = Wt + (size_t)((bn >> 4) + w * 2 + c) * 16384 + lane * 8;
    }

    floatx4 acc[4][4];
#pragma unroll
    for (int i = 0; i < 4; ++i)
#pragma unroll
        for (int j = 0; j < 4; ++j)
            acc[i][j] = (floatx4){0.f, 0.f, 0.f, 0.f};

    // prologue: stage tile 0 (oldest 4 loads), then tile 1
#pragma unroll
    for (int c = 0; c < 2; ++c) {
        gload_lds16(ga[c], &As[0][w * 2 + c][0]);
        gload_lds16(gb[c], &Bs[0][w * 2 + c][0]);
    }
#pragma unroll
    for (int c = 0; c < 2; ++c) {
        gload_lds16(ga[c] + 512, &As[1][w * 2 + c][0]);
        gload_lds16(gb[c] + 512, &Bs[1][w * 2 + c][0]);
    }
    asm volatile("s_waitcnt vmcnt(4)" ::: "memory");  // tile 0 landed
    __builtin_amdgcn_s_barrier();

    for (int tt = 0; tt < 30; tt += 3) {
        QKV_STEP(0, 2, tt + 2, true, 4);
        QKV_STEP(1, 0, tt + 3, true, 4);
        QKV_STEP(2, 1, tt + 4, true, 4);
    }
    QKV_STEP(0, 0, 0, false, 0);   // t=30: drain tile 31
    QKV_STEP(1, 0, 0, false, -1);  // t=31: no wait, no barrier

    if (z == 2) {
        // v -> per-bh (d,t) frag-swizzle; 4 consecutive t at fixed d = half4
#pragma unroll
        for (int j = 0; j < 4; ++j) {
            const int col = bn + wc * 64 + j * 16 + l15;
            const int h  = col >> 6;
            const float bj = bias[col];
#pragma unroll
            for (int i = 0; i < 4; ++i) {
                const int t0 = bm + wr * 64 + i * 16 + quad * 4;
                const int bh = (t0 >> 10) * 16 + h;
                const int tm = t0 & 1023;
                half4 pk;
#pragma unroll
                for (int r = 0; r < 4; ++r) pk[r] = (_Float16)(acc[i][j][r] + bj);
                *(half4*)(p.vt + (size_t)bh * 65536 + (size_t)j * 16384
                          + (tm >> 3) * 128 + l15 * 8 + (tm & 7)) = pk;
            }
        }
    } else {
        // q/k -> per-bh (t,d) frag-swizzle
        _Float16* outp = (z == 0) ? p.qb : p.kb;
#pragma unroll
        for (int j = 0; j < 4; ++j) {
            const int col = bn + wc * 64 + j * 16 + l15;
            const int h  = col >> 6;
            const int dd = col & 63;
            const float bj = bias[col];
            const int doff = (dd >> 3) * 128 + (dd & 7);
#pragma unroll
            for (int i = 0; i < 4; ++i) {
#pragma unroll
                for (int r = 0; r < 4; ++r) {
                    const int tg = bm + wr * 64 + i * 16 + quad * 4 + r;
                    const int bh = (tg >> 10) * 16 + h;
                    const int tm = tg & 1023;
                    outp[(size_t)bh * 65536 + (tm >> 4) * 1024 + doff + (tm & 15) * 8] =
                        (_Float16)(acc[i][j][r] + bj);
                }
            }
        }
    }
}

// ---------------------------------------------------------------------------
// attn_mfma (round-10 configuration — verified; round-11's 512-thread variant
// doubled K/V traffic and regressed). BARRIER-FREE: frag-direct Q/K/V loads,
// wave-private P in LDS, fixed-max softmax + ones-MFMA row sums.
// 4 waves x 32 q-rows, 128 q-rows/block; grid (64,8) x 256: x = bh.
// ---------------------------------------------------------------------------
__global__ __launch_bounds__(256) void attn_mfma(
    const _Float16* __restrict__ qb, const _Float16* __restrict__ kb,
    const _Float16* __restrict__ vt, const float* __restrict__ padj,
    _Float16* __restrict__ yh)
{
    __shared__ __align__(16) _Float16 Ps[4][2048];  // wave-private P

    const int tid  = threadIdx.x;
    const int lane = tid & 63;
    const int w    = tid >> 6;
    const int quad = lane >> 4;
    const int l15  = lane & 15;
    const int bh   = blockIdx.x;
    const int q0   = blockIdx.y * 128;
    const int b    = bh >> 4;
    const int h    = bh & 15;

    const _Float16* qf = qb + (size_t)bh * 65536;
    const _Float16* kf = kb + (size_t)bh * 65536;
    const _Float16* vf = vt + (size_t)bh * 65536;
    const float*    pk_row = padj + b * Tt;

    // Q frags: register-resident for entire K-loop (B-operand of S^T)
    half8 bq[2][2];
#pragma unroll
    for (int ks = 0; ks < 2; ++ks)
#pragma unroll
        for (int nq = 0; nq < 2; ++nq)
            bq[ks][nq] = *(const half8*)(qf + (size_t)((q0 >> 4) + w * 2 + nq) * 1024
                                         + ks * 512 + lane * 8);
    float kq[2];
#pragma unroll
    for (int nq = 0; nq < 2; ++nq)
        kq[nq] = 1.0f - pk_row[q0 + w * 32 + nq * 16 + l15];

    floatx4 O[2][4];
    floatx4 l_acc[2];
#pragma unroll
    for (int mi = 0; mi < 2; ++mi) {
#pragma unroll
        for (int dj = 0; dj < 4; ++dj) O[mi][dj] = (floatx4){0.f, 0.f, 0.f, 0.f};
        l_acc[mi] = (floatx4){0.f, 0.f, 0.f, 0.f};
    }
    half8 ones;
#pragma unroll
    for (int j = 0; j < 8; ++j) ones[j] = (_Float16)1.0f;

    constexpr float SC = 0.18033688011112042f;  // 0.125 * log2(e)

    for (int kt = 0; kt < Tt; kt += 64) {
        // direct frag loads: K (A-operand), V (B-operand)
        half8 ak[2][4], bv[2][4];
#pragma unroll
        for (int ks = 0; ks < 2; ++ks)
#pragma unroll
            for (int mk = 0; mk < 4; ++mk)
                ak[ks][mk] = *(const half8*)(kf + (size_t)((kt >> 4) + mk) * 1024
                                             + ks * 512 + lane * 8);
#pragma unroll
        for (int ks = 0; ks < 2; ++ks)
#pragma unroll
            for (int dj = 0; dj < 4; ++dj)
                bv[ks][dj] = *(const half8*)(vf + (size_t)dj * 16384 + (kt >> 3) * 128
                                             + ks * 512 + lane * 8);
        float4 kk4[4];
#pragma unroll
        for (int mk = 0; mk < 4; ++mk)
            kk4[mk] = *(const float4*)(pk_row + kt + mk * 16 + quad * 4);

        // S^T = K Q^T : C[m=key(quad*4+r)][n=qrow(l15)]
        floatx4 ST[4][2];
#pragma unroll
        for (int mk = 0; mk < 4; ++mk)
#pragma unroll
            for (int nq = 0; nq < 2; ++nq)
                ST[mk][nq] = (floatx4){0.f, 0.f, 0.f, 0.f};
#pragma unroll
        for (int ks = 0; ks < 2; ++ks)
#pragma unroll
            for (int mk = 0; mk < 4; ++mk)
#pragma unroll
                for (int nq = 0; nq < 2; ++nq)
                    ST[mk][nq] = __builtin_amdgcn_mfma_f32_16x16x32_f16(
                        ak[ks][mk], bq[ks][nq], ST[mk][nq], 0, 0, 0);

        // fixed-max softmax + wave-private P write (conflict-free b64)
#pragma unroll
        for (int mk = 0; mk < 4; ++mk) {
            const float kkr[4] = {1.0f - kk4[mk].x, 1.0f - kk4[mk].y,
                                  1.0f - kk4[mk].z, 1.0f - kk4[mk].w};
#pragma unroll
            for (int nq = 0; nq < 2; ++nq) {
                half4 pk;
#pragma unroll
                for (int r = 0; r < 4; ++r) {
                    const float e = __builtin_amdgcn_exp2f(ST[mk][nq][r] * SC);
                    const float pv = (kq[nq] == 0.0f) ? 1.0f : kkr[r] * e;
                    pk[r] = (_Float16)pv;
                }
                *(half4*)&Ps[w][((mk * 2 + (quad >> 1)) * 32 + nq * 16 + l15) * 8
                               + (quad & 1) * 4] = pk;
            }
        }
        // same-wave RAW on Ps -> compiler lgkmcnt; no barrier needed

        // O += P V ; l += P @ ones
#pragma unroll
        for (int ks = 0; ks < 2; ++ks) {
            half8 ap[2];
#pragma unroll
            for (int mi = 0; mi < 2; ++mi)
                ap[mi] = *(const half8*)&Ps[w][((ks * 4 + quad) * 32 + mi * 16 + l15) * 8];
#pragma unroll
            for (int mi = 0; mi < 2; ++mi) {
#pragma unroll
                for (int dj = 0; dj < 4; ++dj)
                    O[mi][dj] = __builtin_amdgcn_mfma_f32_16x16x32_f16(
                        ap[mi], bv[ks][dj], O[mi][dj], 0, 0, 0);
                l_acc[mi] = __builtin_amdgcn_mfma_f32_16x16x32_f16(
                    ap[mi], ones, l_acc[mi], 0, 0, 0);
            }
        }
    }

    // epilogue: normalize, write yh frag-swizzled (for LDS-free proj)
#pragma unroll
    for (int mi = 0; mi < 2; ++mi) {
#pragma unroll
        for (int r = 0; r < 4; ++r) {
            const int rowl  = w * 32 + mi * 16 + quad * 4 + r;
            const int token = b * Tt + q0 + rowl;
            const float inv = 1.0f / l_acc[mi][r];
            const size_t tb = (size_t)(token >> 4) * 16384 + (token & 15) * 8;
#pragma unroll
            for (int dj = 0; dj < 4; ++dj) {
                const int col = h * 64 + dj * 16 + l15;
                yh[tb + (col >> 3) * 128 + (col & 7)] = (_Float16)(O[mi][dj][r] * inv);
            }
        }
    }
}

// ---------------------------------------------------------------------------
// gemm_proj: LDS-free frag-direct (round 9/10, verified). 128x64 tiles,
// grid (32,16) = 512 blocks, x = m-tile.
// ---------------------------------------------------------------------------
__global__ __launch_bounds__(256) void gemm_proj(const _Float16* __restrict__ Ay,
                                                 const _Float16* __restrict__ Bt,
                                                 const float* __restrict__ bias,
                                                 float* __restrict__ out)
{
    const int tid  = threadIdx.x;
    const int lane = tid & 63;
    const int w    = tid >> 6;
    const int quad = lane >> 4;
    const int l15  = lane & 15;
    const int bm   = blockIdx.x * 128;
    const int bn   = blockIdx.y * 64;

    const _Float16* Ap[2];
    const _Float16* Bp[4];
#pragma unroll
    for (int i = 0; i < 2; ++i)
        Ap[i] = Ay + (size_t)((bm >> 4) + w * 2 + i) * 16384 + lane * 8;
#pragma unroll
    for (int j = 0; j < 4; ++j)
        Bp[j] = Bt + (size_t)((bn >> 4) + j) * 16384 + lane * 8;

    floatx4 acc[2][4];
#pragma unroll
    for (int i = 0; i < 2; ++i)
#pragma unroll
        for (int j = 0; j < 4; ++j)
            acc[i][j] = (floatx4){0.f, 0.f, 0.f, 0.f};

    half8 a0[2], b0[4];
#pragma unroll
    for (int i = 0; i < 2; ++i) a0[i] = *(const half8*)(Ap[i]);
#pragma unroll
    for (int j = 0; j < 4; ++j) b0[j] = *(const half8*)(Bp[j]);

    for (int kt = 0; kt < 1024; kt += 64) {
        half8 a1[2], b1[4];
        const size_t o1 = (size_t)(kt + 32) * 16;
#pragma unroll
        for (int i = 0; i < 2; ++i) a1[i] = *(const half8*)(Ap[i] + o1);
#pragma unroll
        for (int j = 0; j < 4; ++j) b1[j] = *(const half8*)(Bp[j] + o1);
#pragma unroll
        for (int i = 0; i < 2; ++i)
#pragma unroll
            for (int j = 0; j < 4; ++j)
                acc[i][j] = __builtin_amdgcn_mfma_f32_16x16x32_f16(a0[i], b0[j], acc[i][j], 0, 0, 0);

        const size_t o2 = (kt + 64 < 1024) ? (size_t)(kt + 64) * 16 : 0;
#pragma unroll
        for (int i = 0; i < 2; ++i) a0[i] = *(const half8*)(Ap[i] + o2);
#pragma unroll
        for (int j = 0; j < 4; ++j) b0[j] = *(const half8*)(Bp[j] + o2);
#pragma unroll
        for (int i = 0; i < 2; ++i)
#pragma unroll
            for (int j = 0; j < 4; ++j)
                acc[i][j] = __builtin_amdgcn_mfma_f32_16x16x32_f16(a1[i], b1[j], acc[i][j], 0, 0, 0);
    }

#pragma unroll
    for (int j = 0; j < 4; ++j) {
        const int col = bn + j * 16 + l15;
        const float bj = bias[col];
#pragma unroll
        for (int i = 0; i < 2; ++i) {
            const int row = bm + w * 32 + i * 16 + quad * 4;
            float* o = out + (size_t)row * 1024 + col;
#pragma unroll
            for (int r = 0; r < 4; ++r)
                o[(size_t)r * 1024] = acc[i][j][r] + bj;
        }
    }
}

// ---------------------------------------------------------------------------
extern "C" void kernel_launch(void* const* d_in, const int* in_sizes, int n_in,
                              void* d_out, int out_size, void* d_ws, size_t ws_size,
                              hipStream_t stream)
{
    const float* x    = (const float*)d_in[0];
    const float* padj = (const float*)d_in[1];
    const float* Wq   = (const float*)d_in[2];
    const float* bq   = (const float*)d_in[3];
    const float* Wk   = (const float*)d_in[4];
    const float* bk   = (const float*)d_in[5];
    const float* Wv   = (const float*)d_in[6];
    const float* bv   = (const float*)d_in[7];
    const float* Wp   = (const float*)d_in[8];
    const float* bp   = (const float*)d_in[9];
    float* out = (float*)d_out;

    const size_t MB = 1024 * 1024;
    char* ws = (char*)d_ws;
    _Float16* xh  = (_Float16*)(ws);            //  8 MB (frag-swizzled)
    _Float16* Wt0 = (_Float16*)(ws +  8 * MB);  //  2 MB
    _Float16* Wt1 = (_Float16*)(ws + 10 * MB);  //  2 MB
    _Float16* Wt2 = (_Float16*)(ws + 12 * MB);  //  2 MB
    _Float16* Wtp = (_Float16*)(ws + 14 * MB);  //  2 MB
    _Float16* qb  = (_Float16*)(ws + 16 * MB);  //  8 MB (per-bh frag)
    _Float16* kb  = (_Float16*)(ws + 24 * MB);  //  8 MB (per-bh frag)
    _Float16* vtb = (_Float16*)(ws + 32 * MB);  //  8 MB (per-bh frag)
    _Float16* yh  = (_Float16*)(ws + 40 * MB);  //  8 MB (frag-swizzled) -> 48 MB

    PrepP pp;
    pp.x = x; pp.xh = xh;
    pp.W[0] = Wq; pp.W[1] = Wk; pp.W[2] = Wv; pp.W[3] = Wp;
    pp.out[0] = Wt0; pp.out[1] = Wt1; pp.out[2] = Wt2; pp.out[3] = Wtp;
    prep_all<<<1280, 256, 0, stream>>>(pp);

    QkvP qp;
    qp.Wt[0] = Wt0; qp.Wt[1] = Wt1; qp.Wt[2] = Wt2;
    qp.bias[0] = bq; qp.bias[1] = bk; qp.bias[2] = bv;
    qp.qb = qb; qp.kb = kb; qp.vt = vtb;
    gemm_qkv<<<dim3(32, 8, 3), 256, 0, stream>>>(xh, qp);

    attn_mfma<<<dim3(64, 8), 256, 0, stream>>>(qb, kb, vtb, padj, yh);

    gemm_proj<<<dim3(32, 16), 256, 0, stream>>>(yh, Wtp, bp, out);
}

// Round 7
// 175.787 us; speedup vs baseline: 1.1058x; 1.0457x over previous
//
#include <hip/hip_runtime.h>
#include <hip/hip_bf16.h>
#include <math.h>

// Problem constants
#define Bb 4
#define Tt 1024
#define Cc 1024
#define Hh 16
#define Dd 64

typedef __attribute__((ext_vector_type(8))) _Float16 half8;
typedef __attribute__((ext_vector_type(4))) _Float16 half4;
typedef __attribute__((ext_vector_type(4))) float floatx4;

// Fragment-swizzled layout for an [R x 1024] f16 matrix:
//   addr(row,k) = (row>>4)*16384 + (k>>3)*128 + (row&15)*8 + (k&7)
// A wave's 16x16x32-MFMA operand fragment (rows 16-aligned, k 32-aligned) is
// base + lane*8 elems -> one coalesced global_load_dwordx4, and each fragment
// is 1024 B CONTIGUOUS -> global_load_lds stages it as a linear copy.

__device__ __forceinline__ void gload_lds16(const _Float16* g, const _Float16* l)
{
    __builtin_amdgcn_global_load_lds(
        (const __attribute__((address_space(1))) void*)g,
        (__attribute__((address_space(3))) void*)l, 16, 0, 0);
}

// ---------------------------------------------------------------------------
// prep_all: merged convert + weight-prep (one dispatch; round-11 verified).
// blocks [0,256):    x fp32 [4096][1024] -> xh f16 frag-swizzled
// blocks [256,1280): W[z][1024][1024] fp32 -> Wt[z] f16 transposed+swizzled
// ---------------------------------------------------------------------------
struct PrepP { const float* x; _Float16* xh; const float* W[4]; _Float16* out[4]; };

__global__ __launch_bounds__(256) void prep_all(PrepP p)
{
    if (blockIdx.x < 256) {
        const int m16 = blockIdx.x;
        const int r   = threadIdx.x & 15;
        const int kc0 = threadIdx.x >> 4;
        const float* src = p.x + (size_t)(m16 * 16 + r) * 1024;
        _Float16*   dst = p.xh + (size_t)m16 * 16384 + r * 8;
#pragma unroll
        for (int c8 = 0; c8 < 8; ++c8) {
            const int kc = kc0 + c8 * 16;
            float4 a = *(const float4*)(src + kc * 8);
            float4 b = *(const float4*)(src + kc * 8 + 4);
            half8 h;
            h[0] = (_Float16)a.x; h[1] = (_Float16)a.y; h[2] = (_Float16)a.z; h[3] = (_Float16)a.w;
            h[4] = (_Float16)b.x; h[5] = (_Float16)b.y; h[6] = (_Float16)b.z; h[7] = (_Float16)b.w;
            *(half8*)(dst + kc * 128) = h;
        }
        return;
    }
    const int bid2 = blockIdx.x - 256;
    const int z    = bid2 >> 8;
    const int rem  = bid2 & 255;
    const int n0   = (rem & 15) * 64;
    const int k0   = (rem >> 4) * 64;
    const float* __restrict__ W = p.W[z];
    _Float16* __restrict__ outp = p.out[z];
    __shared__ float tile[64][65];
    const int tr  = threadIdx.x >> 4;
    const int tc4 = (threadIdx.x & 15) * 4;

#pragma unroll
    for (int i = 0; i < 4; ++i) {
        const int kk = tr + i * 16;
        float4 v = *(const float4*)(W + (size_t)(k0 + kk) * 1024 + n0 + tc4);
        tile[kk][tc4 + 0] = v.x;
        tile[kk][tc4 + 1] = v.y;
        tile[kk][tc4 + 2] = v.z;
        tile[kk][tc4 + 3] = v.w;
    }
    __syncthreads();
#pragma unroll
    for (int i = 0; i < 4; ++i) {
        half4 h;
#pragma unroll
        for (int c = 0; c < 4; ++c) h[c] = (_Float16)tile[tc4 + c][tr + i * 16];
        _Float16* dst = outp + (size_t)((n0 >> 4) + i) * 16384
                        + ((k0 + tc4) >> 3) * 128 + tr * 8 + (tc4 & 7);
        *(half4*)dst = h;
    }
}

// ---------------------------------------------------------------------------
// gemm_qkv: ROUND-6 — 8-wave 128^2 block (512 threads), same T3+T4
// counted-vmcnt 3-buffer pipeline as round-4 (verified correct, 43 us).
// Evidence: r2/r4 both ~43-45 us, MfmaUtil+VALUBusy ~44% -> wait-bound at
// 12 waves/CU (grid-limited 3 blocks/CU). 8 waves/block doubles residency
// to 24 waves/CU at constant grid/LDS/traffic. Per-wave tile 32x64:
// 2 A + 4 B ds_reads, 8 MFMA, acc[2][4]; wave w stages A-frag w + B-frag w
// (2 loads/tile/wave -> ledger: vmcnt(2) steady, vmcnt(0) at t=30).
// Output epilogue/layouts unchanged (i-range halved).
// ---------------------------------------------------------------------------
struct QkvP { const _Float16* Wt[3]; const float* bias[3];
              _Float16* qb; _Float16* kb; _Float16* vt; };

#define QKV_STEP(CUR, SBUF, TS, DOSTAGE, TAILWAIT)                          \
    {                                                                       \
        half8 af[2], bf[4];                                                 \
        _Pragma("unroll")                                                   \
        for (int i = 0; i < 2; ++i)                                         \
            af[i] = *(const half8*)&As[CUR][wr * 2 + i][lane * 8];          \
        _Pragma("unroll")                                                   \
        for (int j = 0; j < 4; ++j)                                         \
            bf[j] = *(const half8*)&Bs[CUR][wc * 4 + j][lane * 8];          \
        if (DOSTAGE) {                                                      \
            const size_t ko = (size_t)(TS) * 512;                           \
            gload_lds16(ga + ko, &As[SBUF][w][0]);                          \
            gload_lds16(gb + ko, &Bs[SBUF][w][0]);                          \
        }                                                                   \
        _Pragma("unroll")                                                   \
        for (int i = 0; i < 2; ++i)                                         \
            _Pragma("unroll")                                               \
            for (int j = 0; j < 4; ++j)                                     \
                acc[i][j] = __builtin_amdgcn_mfma_f32_16x16x32_f16(         \
                    af[i], bf[j], acc[i][j], 0, 0, 0);                      \
        if ((TAILWAIT) == 2)                                                \
            asm volatile("s_waitcnt vmcnt(2)" ::: "memory");                \
        else if ((TAILWAIT) == 0)                                           \
            asm volatile("s_waitcnt vmcnt(0)" ::: "memory");                \
        if ((TAILWAIT) >= 0) __builtin_amdgcn_s_barrier();                  \
    }

__global__ __launch_bounds__(512) void gemm_qkv(const _Float16* __restrict__ xh, QkvP p)
{
    const int z = blockIdx.z;
    const _Float16* __restrict__ Wt   = p.Wt[z];
    const float* __restrict__    bias = p.bias[z];

    const int tid  = threadIdx.x;
    const int lane = tid & 63;
    const int w    = tid >> 6;        // 8 waves
    const int wr   = w >> 1, wc = w & 1;   // 4M x 2N wave grid
    const int quad = lane >> 4;
    const int l15  = lane & 15;
    const int bm   = blockIdx.x * 128;
    const int bn   = blockIdx.y * 128;

    // triple-buffered BK=32 tiles: 8 A-frags + 8 B-frags of 1 KB per buffer
    __shared__ __align__(16) _Float16 As[3][8][512];
    __shared__ __align__(16) _Float16 Bs[3][8][512];

    // wave w stages A-frag w and B-frag w: 2 loads/tile
    const _Float16* ga = xh + (size_t)((bm >> 4) + w) * 16384 + lane * 8;
    const _Float16* gb = Wt + (size_t)((bn >> 4) + w) * 16384 + lane * 8;

    floatx4 acc[2][4];
#pragma unroll
    for (int i = 0; i < 2; ++i)
#pragma unroll
        for (int j = 0; j < 4; ++j)
            acc[i][j] = (floatx4){0.f, 0.f, 0.f, 0.f};

    // prologue: stage tile 0 (oldest 2 loads), then tile 1
    gload_lds16(ga, &As[0][w][0]);
    gload_lds16(gb, &Bs[0][w][0]);
    gload_lds16(ga + 512, &As[1][w][0]);
    gload_lds16(gb + 512, &Bs[1][w][0]);
    asm volatile("s_waitcnt vmcnt(2)" ::: "memory");  // tile 0 landed
    __builtin_amdgcn_s_barrier();

    for (int tt = 0; tt < 30; tt += 3) {
        QKV_STEP(0, 2, tt + 2, true, 2);
        QKV_STEP(1, 0, tt + 3, true, 2);
        QKV_STEP(2, 1, tt + 4, true, 2);
    }
    QKV_STEP(0, 0, 0, false, 0);   // t=30: drain tile 31
    QKV_STEP(1, 0, 0, false, -1);  // t=31: no wait, no barrier

    if (z == 2) {
        // v -> per-bh (d,t) frag-swizzle; 4 consecutive t at fixed d = half4
#pragma unroll
        for (int j = 0; j < 4; ++j) {
            const int col = bn + wc * 64 + j * 16 + l15;
            const int h  = col >> 6;
            const float bj = bias[col];
#pragma unroll
            for (int i = 0; i < 2; ++i) {
                const int t0 = bm + wr * 32 + i * 16 + quad * 4;
                const int bh = (t0 >> 10) * 16 + h;
                const int tm = t0 & 1023;
                half4 pk;
#pragma unroll
                for (int r = 0; r < 4; ++r) pk[r] = (_Float16)(acc[i][j][r] + bj);
                *(half4*)(p.vt + (size_t)bh * 65536 + (size_t)j * 16384
                          + (tm >> 3) * 128 + l15 * 8 + (tm & 7)) = pk;
            }
        }
    } else {
        // q/k -> per-bh (t,d) frag-swizzle
        _Float16* outp = (z == 0) ? p.qb : p.kb;
#pragma unroll
        for (int j = 0; j < 4; ++j) {
            const int col = bn + wc * 64 + j * 16 + l15;
            const int h  = col >> 6;
            const int dd = col & 63;
            const float bj = bias[col];
            const int doff = (dd >> 3) * 128 + (dd & 7);
#pragma unroll
            for (int i = 0; i < 2; ++i) {
#pragma unroll
                for (int r = 0; r < 4; ++r) {
                    const int tg = bm + wr * 32 + i * 16 + quad * 4 + r;
                    const int bh = (tg >> 10) * 16 + h;
                    const int tm = tg & 1023;
                    outp[(size_t)bh * 65536 + (tm >> 4) * 1024 + doff + (tm & 15) * 8] =
                        (_Float16)(acc[i][j][r] + bj);
                }
            }
        }
    }
}

// ---------------------------------------------------------------------------
// attn_mfma (round-10 configuration — verified; round-11's 512-thread variant
// doubled K/V traffic and regressed). BARRIER-FREE: frag-direct Q/K/V loads,
// wave-private P in LDS, fixed-max softmax + ones-MFMA row sums.
// 4 waves x 32 q-rows, 128 q-rows/block; grid (64,8) x 256: x = bh.
// ---------------------------------------------------------------------------
__global__ __launch_bounds__(256) void attn_mfma(
    const _Float16* __restrict__ qb, const _Float16* __restrict__ kb,
    const _Float16* __restrict__ vt, const float* __restrict__ padj,
    _Float16* __restrict__ yh)
{
    __shared__ __align__(16) _Float16 Ps[4][2048];  // wave-private P

    const int tid  = threadIdx.x;
    const int lane = tid & 63;
    const int w    = tid >> 6;
    const int quad = lane >> 4;
    const int l15  = lane & 15;
    const int bh   = blockIdx.x;
    const int q0   = blockIdx.y * 128;
    const int b    = bh >> 4;
    const int h    = bh & 15;

    const _Float16* qf = qb + (size_t)bh * 65536;
    const _Float16* kf = kb + (size_t)bh * 65536;
    const _Float16* vf = vt + (size_t)bh * 65536;
    const float*    pk_row = padj + b * Tt;

    // Q frags: register-resident for entire K-loop (B-operand of S^T)
    half8 bq[2][2];
#pragma unroll
    for (int ks = 0; ks < 2; ++ks)
#pragma unroll
        for (int nq = 0; nq < 2; ++nq)
            bq[ks][nq] = *(const half8*)(qf + (size_t)((q0 >> 4) + w * 2 + nq) * 1024
                                         + ks * 512 + lane * 8);
    float kq[2];
#pragma unroll
    for (int nq = 0; nq < 2; ++nq)
        kq[nq] = 1.0f - pk_row[q0 + w * 32 + nq * 16 + l15];

    floatx4 O[2][4];
    floatx4 l_acc[2];
#pragma unroll
    for (int mi = 0; mi < 2; ++mi) {
#pragma unroll
        for (int dj = 0; dj < 4; ++dj) O[mi][dj] = (floatx4){0.f, 0.f, 0.f, 0.f};
        l_acc[mi] = (floatx4){0.f, 0.f, 0.f, 0.f};
    }
    half8 ones;
#pragma unroll
    for (int j = 0; j < 8; ++j) ones[j] = (_Float16)1.0f;

    constexpr float SC = 0.18033688011112042f;  // 0.125 * log2(e)

    for (int kt = 0; kt < Tt; kt += 64) {
        // direct frag loads: K (A-operand), V (B-operand)
        half8 ak[2][4], bv[2][4];
#pragma unroll
        for (int ks = 0; ks < 2; ++ks)
#pragma unroll
            for (int mk = 0; mk < 4; ++mk)
                ak[ks][mk] = *(const half8*)(kf + (size_t)((kt >> 4) + mk) * 1024
                                             + ks * 512 + lane * 8);
#pragma unroll
        for (int ks = 0; ks < 2; ++ks)
#pragma unroll
            for (int dj = 0; dj < 4; ++dj)
                bv[ks][dj] = *(const half8*)(vf + (size_t)dj * 16384 + (kt >> 3) * 128
                                             + ks * 512 + lane * 8);
        float4 kk4[4];
#pragma unroll
        for (int mk = 0; mk < 4; ++mk)
            kk4[mk] = *(const float4*)(pk_row + kt + mk * 16 + quad * 4);

        // S^T = K Q^T : C[m=key(quad*4+r)][n=qrow(l15)]
        floatx4 ST[4][2];
#pragma unroll
        for (int mk = 0; mk < 4; ++mk)
#pragma unroll
            for (int nq = 0; nq < 2; ++nq)
                ST[mk][nq] = (floatx4){0.f, 0.f, 0.f, 0.f};
#pragma unroll
        for (int ks = 0; ks < 2; ++ks)
#pragma unroll
            for (int mk = 0; mk < 4; ++mk)
#pragma unroll
                for (int nq = 0; nq < 2; ++nq)
                    ST[mk][nq] = __builtin_amdgcn_mfma_f32_16x16x32_f16(
                        ak[ks][mk], bq[ks][nq], ST[mk][nq], 0, 0, 0);

        // fixed-max softmax + wave-private P write (conflict-free b64)
#pragma unroll
        for (int mk = 0; mk < 4; ++mk) {
            const float kkr[4] = {1.0f - kk4[mk].x, 1.0f - kk4[mk].y,
                                  1.0f - kk4[mk].z, 1.0f - kk4[mk].w};
#pragma unroll
            for (int nq = 0; nq < 2; ++nq) {
                half4 pk;
#pragma unroll
                for (int r = 0; r < 4; ++r) {
                    const float e = __builtin_amdgcn_exp2f(ST[mk][nq][r] * SC);
                    const float pv = (kq[nq] == 0.0f) ? 1.0f : kkr[r] * e;
                    pk[r] = (_Float16)pv;
                }
                *(half4*)&Ps[w][((mk * 2 + (quad >> 1)) * 32 + nq * 16 + l15) * 8
                               + (quad & 1) * 4] = pk;
            }
        }
        // same-wave RAW on Ps -> compiler lgkmcnt; no barrier needed

        // O += P V ; l += P @ ones
#pragma unroll
        for (int ks = 0; ks < 2; ++ks) {
            half8 ap[2];
#pragma unroll
            for (int mi = 0; mi < 2; ++mi)
                ap[mi] = *(const half8*)&Ps[w][((ks * 4 + quad) * 32 + mi * 16 + l15) * 8];
#pragma unroll
            for (int mi = 0; mi < 2; ++mi) {
#pragma unroll
                for (int dj = 0; dj < 4; ++dj)
                    O[mi][dj] = __builtin_amdgcn_mfma_f32_16x16x32_f16(
                        ap[mi], bv[ks][dj], O[mi][dj], 0, 0, 0);
                l_acc[mi] = __builtin_amdgcn_mfma_f32_16x16x32_f16(
                    ap[mi], ones, l_acc[mi], 0, 0, 0);
            }
        }
    }

    // epilogue: normalize, write yh frag-swizzled (for LDS-free proj)
#pragma unroll
    for (int mi = 0; mi < 2; ++mi) {
#pragma unroll
        for (int r = 0; r < 4; ++r) {
            const int rowl  = w * 32 + mi * 16 + quad * 4 + r;
            const int token = b * Tt + q0 + rowl;
            const float inv = 1.0f / l_acc[mi][r];
            const size_t tb = (size_t)(token >> 4) * 16384 + (token & 15) * 8;
#pragma unroll
            for (int dj = 0; dj < 4; ++dj) {
                const int col = h * 64 + dj * 16 + l15;
                yh[tb + (col >> 3) * 128 + (col & 7)] = (_Float16)(O[mi][dj][r] * inv);
            }
        }
    }
}

// ---------------------------------------------------------------------------
// gemm_proj: LDS-free frag-direct (round 9/10, verified). 128x64 tiles,
// grid (32,16) = 512 blocks, x = m-tile.
// ---------------------------------------------------------------------------
__global__ __launch_bounds__(256) void gemm_proj(const _Float16* __restrict__ Ay,
                                                 const _Float16* __restrict__ Bt,
                                                 const float* __restrict__ bias,
                                                 float* __restrict__ out)
{
    const int tid  = threadIdx.x;
    const int lane = tid & 63;
    const int w    = tid >> 6;
    const int quad = lane >> 4;
    const int l15  = lane & 15;
    const int bm   = blockIdx.x * 128;
    const int bn   = blockIdx.y * 64;

    const _Float16* Ap[2];
    const _Float16* Bp[4];
#pragma unroll
    for (int i = 0; i < 2; ++i)
        Ap[i] = Ay + (size_t)((bm >> 4) + w * 2 + i) * 16384 + lane * 8;
#pragma unroll
    for (int j = 0; j < 4; ++j)
        Bp[j] = Bt + (size_t)((bn >> 4) + j) * 16384 + lane * 8;

    floatx4 acc[2][4];
#pragma unroll
    for (int i = 0; i < 2; ++i)
#pragma unroll
        for (int j = 0; j < 4; ++j)
            acc[i][j] = (floatx4){0.f, 0.f, 0.f, 0.f};

    half8 a0[2], b0[4];
#pragma unroll
    for (int i = 0; i < 2; ++i) a0[i] = *(const half8*)(Ap[i]);
#pragma unroll
    for (int j = 0; j < 4; ++j) b0[j] = *(const half8*)(Bp[j]);

    for (int kt = 0; kt < 1024; kt += 64) {
        half8 a1[2], b1[4];
        const size_t o1 = (size_t)(kt + 32) * 16;
#pragma unroll
        for (int i = 0; i < 2; ++i) a1[i] = *(const half8*)(Ap[i] + o1);
#pragma unroll
        for (int j = 0; j < 4; ++j) b1[j] = *(const half8*)(Bp[j] + o1);
#pragma unroll
        for (int i = 0; i < 2; ++i)
#pragma unroll
            for (int j = 0; j < 4; ++j)
                acc[i][j] = __builtin_amdgcn_mfma_f32_16x16x32_f16(a0[i], b0[j], acc[i][j], 0, 0, 0);

        const size_t o2 = (kt + 64 < 1024) ? (size_t)(kt + 64) * 16 : 0;
#pragma unroll
        for (int i = 0; i < 2; ++i) a0[i] = *(const half8*)(Ap[i] + o2);
#pragma unroll
        for (int j = 0; j < 4; ++j) b0[j] = *(const half8*)(Bp[j] + o2);
#pragma unroll
        for (int i = 0; i < 2; ++i)
#pragma unroll
            for (int j = 0; j < 4; ++j)
                acc[i][j] = __builtin_amdgcn_mfma_f32_16x16x32_f16(a1[i], b1[j], acc[i][j], 0, 0, 0);
    }

#pragma unroll
    for (int j = 0; j < 4; ++j) {
        const int col = bn + j * 16 + l15;
        const float bj = bias[col];
#pragma unroll
        for (int i = 0; i < 2; ++i) {
            const int row = bm + w * 32 + i * 16 + quad * 4;
            float* o = out + (size_t)row * 1024 + col;
#pragma unroll
            for (int r = 0; r < 4; ++r)
                o[(size_t)r * 1024] = acc[i][j][r] + bj;
        }
    }
}

// ---------------------------------------------------------------------------
extern "C" void kernel_launch(void* const* d_in, const int* in_sizes, int n_in,
                              void* d_out, int out_size, void* d_ws, size_t ws_size,
                              hipStream_t stream)
{
    const float* x    = (const float*)d_in[0];
    const float* padj = (const float*)d_in[1];
    const float* Wq   = (const float*)d_in[2];
    const float* bq   = (const float*)d_in[3];
    const float* Wk   = (const float*)d_in[4];
    const float* bk   = (const float*)d_in[5];
    const float* Wv   = (const float*)d_in[6];
    const float* bv   = (const float*)d_in[7];
    const float* Wp   = (const float*)d_in[8];
    const float* bp   = (const float*)d_in[9];
    float* out = (float*)d_out;

    const size_t MB = 1024 * 1024;
    char* ws = (char*)d_ws;
    _Float16* xh  = (_Float16*)(ws);            //  8 MB (frag-swizzled)
    _Float16* Wt0 = (_Float16*)(ws +  8 * MB);  //  2 MB
    _Float16* Wt1 = (_Float16*)(ws + 10 * MB);  //  2 MB
    _Float16* Wt2 = (_Float16*)(ws + 12 * MB);  //  2 MB
    _Float16* Wtp = (_Float16*)(ws + 14 * MB);  //  2 MB
    _Float16* qb  = (_Float16*)(ws + 16 * MB);  //  8 MB (per-bh frag)
    _Float16* kb  = (_Float16*)(ws + 24 * MB);  //  8 MB (per-bh frag)
    _Float16* vtb = (_Float16*)(ws + 32 * MB);  //  8 MB (per-bh frag)
    _Float16* yh  = (_Float16*)(ws + 40 * MB);  //  8 MB (frag-swizzled) -> 48 MB

    PrepP pp;
    pp.x = x; pp.xh = xh;
    pp.W[0] = Wq; pp.W[1] = Wk; pp.W[2] = Wv; pp.W[3] = Wp;
    pp.out[0] = Wt0; pp.out[1] = Wt1; pp.out[2] = Wt2; pp.out[3] = Wtp;
    prep_all<<<1280, 256, 0, stream>>>(pp);

    QkvP qp;
    qp.Wt[0] = Wt0; qp.Wt[1] = Wt1; qp.Wt[2] = Wt2;
    qp.bias[0] = bq; qp.bias[1] = bk; qp.bias[2] = bv;
    qp.qb = qb; qp.kb = kb; qp.vt = vtb;
    gemm_qkv<<<dim3(32, 8, 3), 512, 0, stream>>>(xh, qp);

    attn_mfma<<<dim3(64, 8), 256, 0, stream>>>(qb, kb, vtb, padj, yh);

    gemm_proj<<<dim3(32, 16), 256, 0, stream>>>(yh, Wtp, bp, out);
}